// Round 8
// baseline (1935.361 us; speedup 1.0000x reference)
//
#include <hip/hip_runtime.h>
#include <hip/hip_bf16.h>

// DMN model: GRU encoders + episodic attention + answer GRU.
// B=128 T=512 Tq=32 S=64 G=300 Hd=256 GW=512 V=159 Z=1794
#define B_   128
#define T_   512
#define TQ_  32
#define S_   64
#define G_   300
#define GP_  320      // G padded to mult of 32
#define HD_  256
#define GW_  512
#define V_   159
#define Z_   1794
#define ZP_  1824     // Z padded to mult of 32
#define H3_  768      // 3*Hd

using bf16x8 = __attribute__((ext_vector_type(8))) short;
using bf16x4 = __attribute__((ext_vector_type(4))) short;
using f32x4  = __attribute__((ext_vector_type(4))) float;

// ---- workspace layout (bytes) ----
#define OFF_WIHB_I 0u
#define OFF_WIHB_Q 491520u
#define OFF_GW1B   983040u        // 512x1824 bf16
#define OFF_FACTS  2850816u       // 128x64x256 f32
#define OFF_QVEC   11239424u      // 128x256 f32
#define OFF_UQ     11370496u
#define OFF_UM     11501568u
#define OFF_MT     11632640u
#define OFF_B2I    13139968u      // 768 f32 (bih + bhh for r,z)
#define OFF_B2Q    13143040u      // 768 f32
#define OFF_QBF    13500416u      // 4096x320 bf16 (own region; no Abf alias)
#define OFF_ABF    16777216u
#define OFF_GIQ    20971520u      // 8 chains x 32 t x 512 tid x 24 bf16
#define OFF_Z      29360128u      // 8192x1824 bf16 (ends 59.25 MB)
#define OFF_WMXT   59768832u      // Wih_m^T 256x768 f32
#define OFF_WMHT   60555264u      // Whh_m^T 256x768 f32
#define OFF_WAXT   61341696u      // Wih_a^T 415x768 f32
#define OFF_WAHT   62616576u      // Whh_a^T 256x768 f32 (ends 63.4 MB)
#define OFF_GII    67108864u      // 8 chains x 512 t x 512 tid x 24 bf16 (100.7 MB)
#define OFF_H1     67108864u      // reuses GII region after recurrence

// s_waitcnt immediate: lgkmcnt(0) only (vmcnt=63, expcnt=7 -> no wait)
#define WAIT_LGKM0() __builtin_amdgcn_s_waitcnt(0xC07F)

__device__ __forceinline__ unsigned short f2bf(float f) {
    unsigned int u = __float_as_uint(f);
    u += 0x7fffu + ((u >> 16) & 1u);          // round-to-nearest-even
    return (unsigned short)(u >> 16);
}
__device__ __forceinline__ float bf2f(unsigned short s) {
    return __uint_as_float(((unsigned int)s) << 16);
}
__device__ __forceinline__ float rcpf(float x) { return __builtin_amdgcn_rcpf(x); }
__device__ __forceinline__ float sigm(float x) { return rcpf(1.f + __expf(-x)); }
__device__ __forceinline__ float tanh_fast(float x) {
    float e = __expf(-2.f * fabsf(x));
    float t = (1.f - e) * rcpf(1.f + e);
    return copysignf(t, x);
}

// ---------------- f32 -> bf16 convert with K padding (input only) ----------------
__global__ void conv_pad_kernel(const float* __restrict__ src, unsigned short* __restrict__ dst,
                                int M, int K, int Kp) {
    int i = blockIdx.x * 256 + threadIdx.x;
    if (i >= M * Kp) return;
    int r = i / Kp, c = i - r * Kp;
    dst[i] = (c < K) ? f2bf(src[(size_t)r * K + c]) : (unsigned short)0;
}

// ---------------- merged prep: transposes, bias folds, bf16 weight/Q conversions ----------------
#define S1_ 196608    // 768x256 x3 transposes
#define S2_ 318720    // 768x415 transpose
#define S3_ 768       // bias folds
#define S4_ 245760    // Wihb_i + Wihb_q (768x320)
#define S5_ 933888    // gW1b (512x1824)
#define S6_ 1310720   // Qbf (4096x320)
#define PREP_TOT (S1_ + S2_ + S3_ + S4_ + S5_ + S6_)
__global__ void prep_kernel(
    const float* __restrict__ Wih_m, float* __restrict__ WmxT,
    const float* __restrict__ Whh_m, float* __restrict__ WmhT,
    const float* __restrict__ Wih_a, float* __restrict__ WaxT,
    const float* __restrict__ Whh_a, float* __restrict__ WahT,
    const float* __restrict__ bih_i, const float* __restrict__ bhh_i, float* __restrict__ b2i,
    const float* __restrict__ bih_q, const float* __restrict__ bhh_q, float* __restrict__ b2q,
    const float* __restrict__ Wih_i, unsigned short* __restrict__ Wihb_i,
    const float* __restrict__ Wih_q, unsigned short* __restrict__ Wihb_q,
    const float* __restrict__ gW1,   unsigned short* __restrict__ gW1b,
    const float* __restrict__ Qin,   unsigned short* __restrict__ Qbf)
{
    int i = blockIdx.x * 256 + threadIdx.x;
    if (i < S1_) {
        int r = i / 256, k = i - r * 256;
        WmxT[(size_t)k * 768 + r] = Wih_m[i];
        WmhT[(size_t)k * 768 + r] = Whh_m[i];
        WahT[(size_t)k * 768 + r] = Whh_a[i];
        return;
    }
    i -= S1_;
    if (i < S2_) {
        int r = i / 415, k = i - r * 415;
        WaxT[(size_t)k * 768 + r] = Wih_a[i];
        return;
    }
    i -= S2_;
    if (i < S3_) {
        b2i[i] = bih_i[i] + (i < 512 ? bhh_i[i] : 0.f);
        b2q[i] = bih_q[i] + (i < 512 ? bhh_q[i] : 0.f);
        return;
    }
    i -= S3_;
    if (i < S4_) {
        int r = i / GP_, c = i - r * GP_;
        Wihb_i[i] = (c < G_) ? f2bf(Wih_i[(size_t)r * G_ + c]) : (unsigned short)0;
        Wihb_q[i] = (c < G_) ? f2bf(Wih_q[(size_t)r * G_ + c]) : (unsigned short)0;
        return;
    }
    i -= S4_;
    if (i < S5_) {
        int r = i / ZP_, c = i - r * ZP_;
        gW1b[i] = (c < Z_) ? f2bf(gW1[(size_t)r * Z_ + c]) : (unsigned short)0;
        return;
    }
    i -= S5_;
    if (i < S6_) {
        int r = i / GP_, c = i - r * GP_;
        Qbf[i] = (c < G_) ? f2bf(Qin[(size_t)r * G_ + c]) : (unsigned short)0;
    }
}

// ---------------- bf16 MFMA GEMM: C[M,N] = act(A[M,Kp] @ W[N,Kp]^T + bias) ----------------
// mode 0: plain row-major out. mode 1: GRU gi permute to [c][t][tid][type][tt][i] bf16.
__global__ __launch_bounds__(256) void gemm_bf16_kernel(
    const unsigned short* __restrict__ A, const unsigned short* __restrict__ W,
    const float* __restrict__ bias, void* __restrict__ Cout,
    int M, int N, int Kp, int act, int out_bf16, int mode, int logT)
{
    __shared__ unsigned short As[64][40];
    __shared__ unsigned short Bs[64][40];
    int tid  = threadIdx.x;
    int wv   = tid >> 6, lane = tid & 63;
    int l15  = lane & 15, q = lane >> 4;
    int n0   = blockIdx.x * 64, m0 = blockIdx.y * 64;
    int r    = tid >> 2, p4 = tid & 3;

    const f32x4 zero4 = {0.f, 0.f, 0.f, 0.f};
    f32x4 acc[4] = {zero4, zero4, zero4, zero4};

    for (int k0 = 0; k0 < Kp; k0 += 32) {
        *(int4*)&As[r][p4 * 8] = *(const int4*)&A[(size_t)(m0 + r) * Kp + k0 + p4 * 8];
        *(int4*)&Bs[r][p4 * 8] = *(const int4*)&W[(size_t)(n0 + r) * Kp + k0 + p4 * 8];
        __syncthreads();
        bf16x8 af = *(const bf16x8*)&As[16 * wv + l15][q * 8];
#pragma unroll
        for (int nt = 0; nt < 4; nt++) {
            bf16x8 bf = *(const bf16x8*)&Bs[16 * nt + l15][q * 8];
            acc[nt] = __builtin_amdgcn_mfma_f32_16x16x32_bf16(af, bf, acc[nt], 0, 0, 0);
        }
        __syncthreads();
    }
    int rb = q * 4;
#pragma unroll
    for (int nt = 0; nt < 4; nt++) {
        int cgate = n0 + 16 * nt + l15;
        float bv = bias ? bias[cgate] : 0.f;
#pragma unroll
        for (int i = 0; i < 4; i++) {
            int row = m0 + 16 * wv + rb + i;
            float v = acc[nt][i] + bv;
            if (act == 1) v = tanh_fast(v);
            if (mode == 1) {
                int Tl = 1 << logT;
                int b = row >> logT, t = row & (Tl - 1);
                int cc = b >> 4, l = b & 15;
                int type = cgate >> 8, h = cgate & 255;
                int wvd = h >> 5, off = h & 31;
                int ttd = off >> 4, qd = (off >> 2) & 3, id = off & 3;
                int tidd = wvd * 64 + qd * 16 + l;
                size_t addr = ((size_t)(cc * Tl + t) * 512 + tidd) * 24 + type * 8 + ttd * 4 + id;
                ((unsigned short*)Cout)[addr] = f2bf(v);
            } else if (out_bf16) {
                ((unsigned short*)Cout)[(size_t)row * N + cgate] = f2bf(v);
            } else {
                ((float*)Cout)[(size_t)row * N + cgate] = v;
            }
        }
    }
}

// ---------------- persistent GRU recurrence (merged input+query) ----------------
// 16 blocks x 512 threads (8 waves). Blocks 0-7: input GRU (T=512), 8-15: query (T=32).
// Transposed MFMA: D[m=gate, n=batch]. 5 of 6 weight m-tiles in regs (160 VGPRs);
// n-tt1 tile (64 KB) in dynamic LDS. gi prefetched TWO steps deep (two reg sets,
// 2x-unrolled t loop) -> in-flight window ~2 steps >> HBM latency.
__global__ __launch_bounds__(512, 2) void gru_rec_kernel(
    const float* __restrict__ Whh0, const float* __restrict__ bhh0,
    const unsigned short* __restrict__ gi0, int T0, const int* __restrict__ g0, int GL0,
    float* __restrict__ dst0,
    const float* __restrict__ Whh1, const float* __restrict__ bhh1,
    const unsigned short* __restrict__ gi1, int T1, const int* __restrict__ g1, int GL1,
    float* __restrict__ dst1)
{
    __shared__ unsigned short hfr[2][8][4][16][8];   // [buf][ks][q][batch][j] bf16 (16 KB)
    __shared__ int glist[16 * 64];
    __shared__ int gptr[16], gr0s[2][16], gr1s[2][16];
    extern __shared__ unsigned short wnL[];          // n-gate tt1 weights: [wv*8+ks][lane][8] (64 KB)

    int cb  = blockIdx.x;
    int tid = threadIdx.x;
    int wv  = tid >> 6, lane = tid & 63;
    int l15 = lane & 15, q = lane >> 4;

    const float* Whh; const float* bhh; const unsigned short* gi;
    const int* gidx; float* gdst; int T, GL, isq, c;
    if (cb < 8) { Whh = Whh0; bhh = bhh0; gi = gi0; T = T0; gidx = g0; GL = GL0; isq = 0; gdst = dst0; c = cb; }
    else        { Whh = Whh1; bhh = bhh1; gi = gi1; T = T1; gidx = g1; GL = GL1; isq = 1; gdst = dst1; c = cb - 8; }

    // ---- in-register A-fragments wf[mt][ks], mt: 0=r/tt0 1=r/tt1 2=z/tt0 3=z/tt1 4=n/tt0
    bf16x8 wf[5][8];
#pragma unroll
    for (int mt = 0; mt < 5; mt++) {
        int type = (mt < 4) ? (mt >> 1) : 2;
        int tt   = (mt < 4) ? (mt & 1) : 0;
        int g = type * 256 + 32 * wv + 16 * tt + l15;
#pragma unroll
        for (int ks = 0; ks < 8; ks++) {
            float4 w0 = *(const float4*)&Whh[(size_t)g * 256 + ks * 32 + q * 8];
            float4 w1 = *(const float4*)&Whh[(size_t)g * 256 + ks * 32 + q * 8 + 4];
            bf16x8 v;
            v[0] = (short)f2bf(w0.x); v[1] = (short)f2bf(w0.y);
            v[2] = (short)f2bf(w0.z); v[3] = (short)f2bf(w0.w);
            v[4] = (short)f2bf(w1.x); v[5] = (short)f2bf(w1.y);
            v[6] = (short)f2bf(w1.z); v[7] = (short)f2bf(w1.w);
            wf[mt][ks] = v;
        }
    }
    // ---- n-gate tt1 A-fragments into dynamic LDS (lane-contiguous, conflict-free) ----
    {
        int g = 512 + 32 * wv + 16 + l15;
#pragma unroll
        for (int ks = 0; ks < 8; ks++) {
            float4 w0 = *(const float4*)&Whh[(size_t)g * 256 + ks * 32 + q * 8];
            float4 w1 = *(const float4*)&Whh[(size_t)g * 256 + ks * 32 + q * 8 + 4];
            bf16x8 v;
            v[0] = (short)f2bf(w0.x); v[1] = (short)f2bf(w0.y);
            v[2] = (short)f2bf(w0.z); v[3] = (short)f2bf(w0.w);
            v[4] = (short)f2bf(w1.x); v[5] = (short)f2bf(w1.y);
            v[6] = (short)f2bf(w1.z); v[7] = (short)f2bf(w1.w);
            *(bf16x8*)&wnL[((wv * 8 + ks) * 64 + lane) * 8] = v;
        }
    }
    // bhh_n per-lane -> folded into MFMA C-operand init each step
    float bn[2][4];
#pragma unroll
    for (int tt = 0; tt < 2; tt++)
#pragma unroll
        for (int i = 0; i < 4; i++)
            bn[tt][i] = bhh[512 + 32 * wv + 16 * tt + 4 * q + i];

    // zero h-frag buffer 0 (first 8192 B)
    for (int i2 = tid; i2 < 2048; i2 += 512) ((int*)hfr)[i2] = 0;
    // gather list
    for (int i2 = tid; i2 < 16 * GL; i2 += 512) {
        int b = i2 / GL, s = i2 - b * GL;
        int raw = gidx[(c * 16 + b) * GL + s];
        if (isq) { raw -= 1; if (raw < 0) raw = 0; if (raw > T - 1) raw = T - 1; }
        glist[b * 64 + s] = raw;
    }
    __syncthreads();
    if (tid < 16) {                       // scan for t=0
        int p = 0;
        while (p < GL && glist[tid * 64 + p] == 0) p++;
        gr0s[0][tid] = 0; gr1s[0][tid] = p; gptr[tid] = p;
    }
    __syncthreads();

    float hprev[2][4] = {{0.f, 0.f, 0.f, 0.f}, {0.f, 0.f, 0.f, 0.f}};
    const unsigned short* gib = gi + (size_t)c * T * 12288;   // per-t: 512 tid * 24
    const f32x4 zero4 = {0.f, 0.f, 0.f, 0.f};

    // two prefetch register sets (2-deep pipeline)
    bf16x8 xa0, xb0, xc0, xa1, xb1, xc1;
    {
        const unsigned short* pv = gib + (size_t)tid * 24;
        xa0 = *(const bf16x8*)pv; xb0 = *(const bf16x8*)(pv + 8); xc0 = *(const bf16x8*)(pv + 16);
        const unsigned short* pw = gib + ((size_t)512 + tid) * 24;   // t=1 (T>=2 always)
        xa1 = *(const bf16x8*)pw; xb1 = *(const bf16x8*)(pw + 8); xc1 = *(const bf16x8*)(pw + 16);
    }

    auto do_step = [&](int t, bf16x8& Xa, bf16x8& Xb, bf16x8& Xc) {
        int cur = t & 1, nxt = cur ^ 1;
        // scan gather list for t+1 (writes nxt slot)
        if (tid < 16) {
            int tt1 = t + 1;
            int p = gptr[tid], pp = p;
            while (p < GL && glist[tid * 64 + p] == tt1) p++;
            gr0s[nxt][tid] = pp; gr1s[nxt][tid] = p; gptr[tid] = p;
        }
        // MFMA: acc[mt] = gh[gate][batch=l15]; n-gate C-init = bhh_n
        f32x4 acc[6];
        acc[0] = zero4; acc[1] = zero4; acc[2] = zero4; acc[3] = zero4;
        {
            f32x4 b4 = {bn[0][0], bn[0][1], bn[0][2], bn[0][3]}; acc[4] = b4;
            f32x4 b5 = {bn[1][0], bn[1][1], bn[1][2], bn[1][3]}; acc[5] = b5;
        }
#pragma unroll
        for (int ks = 0; ks < 8; ks++) {
            bf16x8 hb = *(const bf16x8*)&hfr[cur][ks][q][l15][0];
            acc[0] = __builtin_amdgcn_mfma_f32_16x16x32_bf16(wf[0][ks], hb, acc[0], 0, 0, 0);
            acc[1] = __builtin_amdgcn_mfma_f32_16x16x32_bf16(wf[1][ks], hb, acc[1], 0, 0, 0);
            acc[2] = __builtin_amdgcn_mfma_f32_16x16x32_bf16(wf[2][ks], hb, acc[2], 0, 0, 0);
            acc[3] = __builtin_amdgcn_mfma_f32_16x16x32_bf16(wf[3][ks], hb, acc[3], 0, 0, 0);
            acc[4] = __builtin_amdgcn_mfma_f32_16x16x32_bf16(wf[4][ks], hb, acc[4], 0, 0, 0);
            bf16x8 w5 = *(const bf16x8*)&wnL[((wv * 8 + ks) * 64 + lane) * 8];
            acc[5] = __builtin_amdgcn_mfma_f32_16x16x32_bf16(w5, hb, acc[5], 0, 0, 0);
        }
        // elementwise GRU update (registers only)
        float h2a[2][4];
#pragma unroll
        for (int tt = 0; tt < 2; tt++) {
#pragma unroll
            for (int i = 0; i < 4; i++) {
                float r = sigm(bf2f((unsigned short)Xa[tt * 4 + i]) + acc[tt][i]);
                float z = sigm(bf2f((unsigned short)Xb[tt * 4 + i]) + acc[2 + tt][i]);
                float n = tanh_fast(bf2f((unsigned short)Xc[tt * 4 + i]) + r * acc[4 + tt][i]);
                float h2 = (1.f - z) * n + z * hprev[tt][i];
                hprev[tt][i] = h2;
                h2a[tt][i] = h2;
            }
            bf16x4 hb;
#pragma unroll
            for (int i = 0; i < 4; i++) hb[i] = (short)f2bf(h2a[tt][i]);
            int qp = 2 * tt + (q >> 1), jb = 4 * (q & 1);
            *(bf16x4*)&hfr[nxt][wv][qp][l15][jb] = hb;
        }
        // gather writes (EOS / q_seq_len)
        {
            int p0 = gr0s[cur][l15], p1 = gr1s[cur][l15];
            for (int s = p0; s < p1; s++) {
                float* dp = &gdst[((size_t)(c * 16 + l15) * GL + s) * 256 + 32 * wv + 4 * q];
                float4 o0 = {h2a[0][0], h2a[0][1], h2a[0][2], h2a[0][3]};
                float4 o1 = {h2a[1][0], h2a[1][1], h2a[1][2], h2a[1][3]};
                *(float4*)dp        = o0;
                *(float4*)(dp + 16) = o1;
            }
        }
        // prefetch gi for t+2 into the just-consumed set (2-step in-flight window)
        {
            int tn = (t + 2 < T) ? (t + 2) : (T - 1);
            const unsigned short* pv = gib + ((size_t)tn * 512 + tid) * 24;
            Xa = *(const bf16x8*)pv;
            Xb = *(const bf16x8*)(pv + 8);
            Xc = *(const bf16x8*)(pv + 16);
        }
        // single barrier: LDS writes visible; vmcnt NOT drained
        __builtin_amdgcn_sched_barrier(0);
        WAIT_LGKM0();
        __builtin_amdgcn_s_barrier();
        __builtin_amdgcn_sched_barrier(0);
    };

    for (int t = 0; t < T; t += 2) {
        do_step(t,     xa0, xb0, xc0);
        do_step(t + 1, xa1, xb1, xc1);
    }
}

// ---------------- u_q/u_m init + Mt=qvec ----------------
__global__ __launch_bounds__(256) void uvec_kernel(const float* __restrict__ zW,
                                                   const float* __restrict__ v,
                                                   float* __restrict__ u_q,
                                                   float* __restrict__ u_m,
                                                   float* __restrict__ Mt) {
    int b = blockIdx.x, h = threadIdx.x;
    float a = 0.f;
    for (int k = 0; k < 256; k++) a += zW[k * 256 + h] * v[b * 256 + k];
    u_q[b * 256 + h] = a;
    u_m[b * 256 + h] = a;          // Mt(ep0) == qvec
    Mt[b * 256 + h]  = v[b * 256 + h];
}

// ---------------- build z features (bf16, ZP cols) ----------------
__global__ __launch_bounds__(256) void build_z_kernel(
    const float* __restrict__ facts, const float* __restrict__ qv, const float* __restrict__ Mt,
    const float* __restrict__ u_m, const float* __restrict__ u_q, unsigned short* __restrict__ z)
{
    __shared__ float rm[4], rq[4], szm, szq;
    int bs = blockIdx.x;            // b*64+s
    int b  = bs >> 6;
    int j  = threadIdx.x;
    float C  = facts[(size_t)bs * 256 + j];
    float m  = Mt[b * 256 + j];
    float qq = qv[b * 256 + j];
    float dm = C * u_m[b * 256 + j];
    float dq = C * u_q[b * 256 + j];
    for (int o = 32; o; o >>= 1) { dm += __shfl_down(dm, o); dq += __shfl_down(dq, o); }
    int wvi = j >> 6;
    if ((j & 63) == 0) { rm[wvi] = dm; rq[wvi] = dq; }
    __syncthreads();
    if (j == 0) { szm = rm[0] + rm[1] + rm[2] + rm[3]; szq = rq[0] + rq[1] + rq[2] + rq[3]; }
    __syncthreads();
    size_t zr = (size_t)bs * ZP_;
    z[zr + j]        = f2bf(C);
    z[zr + 256 + j]  = f2bf(qq);
    z[zr + 512 + j]  = f2bf(m);
    z[zr + 768 + j]  = f2bf(C * m);
    z[zr + 1024 + j] = f2bf(C * qq);
    z[zr + 1280 + j] = f2bf(fabsf(C - m));
    z[zr + 1536 + j] = f2bf(fabsf(C - qq));
    if (j == 0) { z[zr + 1792] = f2bf(szm); z[zr + 1793] = f2bf(szq); }
    if (j < ZP_ - Z_) z[zr + Z_ + j] = 0;
}

// ---------------- fused episode tail: g-reduce + softmax + Htc + GRU cell + u_m ----------------
// one block per batch row b, 256 threads.
__global__ __launch_bounds__(256) void episode_tail_kernel(
    const float* __restrict__ H1, const float* __restrict__ gW2, const float* __restrict__ gb2,
    const float* __restrict__ facts,
    const float* __restrict__ WmxT, const float* __restrict__ bxm,
    const float* __restrict__ WmhT, const float* __restrict__ bhm,
    const float* __restrict__ zW,
    float* __restrict__ Mt, float* __restrict__ u_m)
{
    __shared__ float red[64][4];
    __shared__ float p64[64];
    __shared__ float xs[256];   // Htc
    __shared__ float hs[256];   // Mt old
    __shared__ float hs2[256];  // Mt new
    int b = blockIdx.x, tid = threadIdx.x;
    // stage 1: att pre-activation partials
    {
        int s = tid >> 2, part = tid & 3;
        const float* h1r = H1 + ((size_t)(b * 64 + s)) * 512 + part * 128;
        const float* w2  = gW2 + part * 128;
        float a = 0.f;
        for (int k = 0; k < 128; k++) a += h1r[k] * w2[k];
        red[s][part] = a;
    }
    hs[tid] = Mt[b * 256 + tid];
    __syncthreads();
    // stage 2: att + softmax over 64 (wave 0)
    if (tid < 64) {
        float att = sigm(red[tid][0] + red[tid][1] + red[tid][2] + red[tid][3] + gb2[0]);
        float mx = att;
        for (int o = 32; o; o >>= 1) mx = fmaxf(mx, __shfl_xor(mx, o));
        float e = __expf(att - mx);
        float sm = e;
        for (int o = 32; o; o >>= 1) sm += __shfl_xor(sm, o);
        p64[tid] = e * rcpf(sm);
    }
    __syncthreads();
    // stage 3: Htc
    {
        float a = 0.f;
        for (int s = 0; s < 64; s++) a += facts[((size_t)b * 64 + s) * 256 + tid] * p64[s];
        xs[tid] = a;
    }
    __syncthreads();
    // stage 4: GRU cell (x=Htc, h=Mt)
    {
        int j = tid;
        float ar = bxm[j], az = bxm[256 + j], an = bxm[512 + j];
        for (int k = 0; k < 256; k++) {
            float xv = xs[k];
            const float* wr = &WmxT[(size_t)k * 768];
            ar += xv * wr[j]; az += xv * wr[256 + j]; an += xv * wr[512 + j];
        }
        float hr = bhm[j], hz = bhm[256 + j], hn = bhm[512 + j];
        for (int k = 0; k < 256; k++) {
            float hv = hs[k];
            const float* wr = &WmhT[(size_t)k * 768];
            hr += hv * wr[j]; hz += hv * wr[256 + j]; hn += hv * wr[512 + j];
        }
        float r = sigm(ar + hr);
        float z = sigm(az + hz);
        float n = tanh_fast(an + r * hn);
        float h2 = (1.f - z) * n + z * hs[j];
        Mt[b * 256 + j] = h2;
        hs2[j] = h2;
    }
    __syncthreads();
    // stage 5: u_m for next episode
    {
        float a = 0.f;
        for (int k = 0; k < 256; k++) a += zW[k * 256 + tid] * hs2[k];
        u_m[b * 256 + tid] = a;
    }
}

// ---------------- fused answer head: softmax(Mt@Wa^T) -> concat(yt, qvec) -> GRU cell -> softmax ----------------
__global__ __launch_bounds__(256) void answer_kernel(
    const float* __restrict__ Mt, const float* __restrict__ Wa, const float* __restrict__ qv,
    const float* __restrict__ WaxT, const float* __restrict__ bxa,
    const float* __restrict__ WahT, const float* __restrict__ bha,
    float* __restrict__ out)
{
    __shared__ float sc[V_];
    __shared__ float xs[416];
    __shared__ float hs[256], hs2[256];
    int b = blockIdx.x, tid = threadIdx.x;
    hs[tid] = Mt[b * 256 + tid];
    xs[V_ + tid] = qv[b * 256 + tid];    // xt[159:415] = q  (reference: concat([yt, q]))
    __syncthreads();
    if (tid < V_) {
        float a = 0.f;
        for (int k = 0; k < 256; k++) a += hs[k] * Wa[(size_t)tid * 256 + k];
        sc[tid] = a;
    }
    __syncthreads();
    if (tid == 0) {
        float mx = -1e30f;
        for (int v = 0; v < V_; v++) mx = fmaxf(mx, sc[v]);
        float sm = 0.f;
        for (int v = 0; v < V_; v++) { float e = __expf(sc[v] - mx); sc[v] = e; sm += e; }
        float inv = rcpf(sm);
        for (int v = 0; v < V_; v++) sc[v] *= inv;
    }
    __syncthreads();
    if (tid < V_) xs[tid] = sc[tid];     // xt[0:159] = yt
    __syncthreads();
    // GRU cell (x=xt[415], h=at=Mt)
    {
        int j = tid;
        float ar = bxa[j], az = bxa[256 + j], an = bxa[512 + j];
        for (int k = 0; k < 415; k++) {
            float xv = xs[k];
            const float* wr = &WaxT[(size_t)k * 768];
            ar += xv * wr[j]; az += xv * wr[256 + j]; an += xv * wr[512 + j];
        }
        float hr = bha[j], hz = bha[256 + j], hn = bha[512 + j];
        for (int k = 0; k < 256; k++) {
            float hv = hs[k];
            const float* wr = &WahT[(size_t)k * 768];
            hr += hv * wr[j]; hz += hv * wr[256 + j]; hn += hv * wr[512 + j];
        }
        float r = sigm(ar + hr);
        float z = sigm(az + hz);
        float n = tanh_fast(an + r * hn);
        hs2[j] = (1.f - z) * n + z * hs[j];
    }
    __syncthreads();
    if (tid < V_) {
        float a = 0.f;
        for (int k = 0; k < 256; k++) a += hs2[k] * Wa[(size_t)tid * 256 + k];
        sc[tid] = a;
    }
    __syncthreads();
    if (tid == 0) {
        float mx = -1e30f;
        for (int v = 0; v < V_; v++) mx = fmaxf(mx, sc[v]);
        float sm = 0.f;
        for (int v = 0; v < V_; v++) { float e = __expf(sc[v] - mx); sc[v] = e; sm += e; }
        float inv = rcpf(sm);
        for (int v = 0; v < V_; v++) sc[v] *= inv;
    }
    __syncthreads();
    if (tid < V_) out[b * V_ + tid] = sc[tid];
}

extern "C" void kernel_launch(void* const* d_in, const int* in_sizes, int n_in,
                              void* d_out, int out_size, void* d_ws, size_t ws_size,
                              hipStream_t stream) {
    (void)in_sizes; (void)n_in; (void)out_size; (void)ws_size;
    const float* input = (const float*)d_in[0];
    const float* Qin   = (const float*)d_in[1];
    const int*   EOS   = (const int*)d_in[2];
    const int*   qsl   = (const int*)d_in[3];
    const float* Wih_i = (const float*)d_in[6];
    const float* Whh_i = (const float*)d_in[7];
    const float* bih_i = (const float*)d_in[8];
    const float* bhh_i = (const float*)d_in[9];
    const float* Wih_q = (const float*)d_in[10];
    const float* Whh_q = (const float*)d_in[11];
    const float* bih_q = (const float*)d_in[12];
    const float* bhh_q = (const float*)d_in[13];
    const float* zW    = (const float*)d_in[14];
    const float* gW1   = (const float*)d_in[15];
    const float* gb1   = (const float*)d_in[16];
    const float* gW2   = (const float*)d_in[17];
    const float* gb2   = (const float*)d_in[18];
    const float* Wih_m = (const float*)d_in[19];
    const float* Whh_m = (const float*)d_in[20];
    const float* bih_m = (const float*)d_in[21];
    const float* bhh_m = (const float*)d_in[22];
    const float* Wa    = (const float*)d_in[23];
    const float* Wih_a = (const float*)d_in[24];
    const float* Whh_a = (const float*)d_in[25];
    const float* bih_a = (const float*)d_in[26];
    const float* bhh_a = (const float*)d_in[27];

    char* ws = (char*)d_ws;
    unsigned short* Wihb_i = (unsigned short*)(ws + OFF_WIHB_I);
    unsigned short* Wihb_q = (unsigned short*)(ws + OFF_WIHB_Q);
    unsigned short* gW1b   = (unsigned short*)(ws + OFF_GW1B);
    float* facts = (float*)(ws + OFF_FACTS);
    float* qvec  = (float*)(ws + OFF_QVEC);
    float* u_q   = (float*)(ws + OFF_UQ);
    float* u_m   = (float*)(ws + OFF_UM);
    float* Mt    = (float*)(ws + OFF_MT);
    float* b2i   = (float*)(ws + OFF_B2I);
    float* b2q   = (float*)(ws + OFF_B2Q);
    float* WmxT  = (float*)(ws + OFF_WMXT);
    float* WmhT  = (float*)(ws + OFF_WMHT);
    float* WaxT  = (float*)(ws + OFF_WAXT);
    float* WahT  = (float*)(ws + OFF_WAHT);
    unsigned short* Abf  = (unsigned short*)(ws + OFF_ABF);
    unsigned short* Qbf  = (unsigned short*)(ws + OFF_QBF);
    unsigned short* gi_q = (unsigned short*)(ws + OFF_GIQ);
    unsigned short* zbf  = (unsigned short*)(ws + OFF_Z);
    unsigned short* gi_i = (unsigned short*)(ws + OFF_GII);
    float* H1 = (float*)(ws + OFF_H1);

    hipFuncSetAttribute((const void*)gru_rec_kernel,
                        hipFuncAttributeMaxDynamicSharedMemorySize, 65536);

    // --- conversions + merged prep ---
    conv_pad_kernel<<<(65536 * GP_ + 255) / 256, 256, 0, stream>>>(input, Abf, 65536, G_, GP_);
    prep_kernel<<<(PREP_TOT + 255) / 256, 256, 0, stream>>>(
        Wih_m, WmxT, Whh_m, WmhT, Wih_a, WaxT, Whh_a, WahT,
        bih_i, bhh_i, b2i, bih_q, bhh_q, b2q,
        Wih_i, Wihb_i, Wih_q, Wihb_q, gW1, gW1b, Qin, Qbf);
    // --- gi GEMMs (output permuted to [c][t][tid][24], bih+bhh(r,z) folded) ---
    gemm_bf16_kernel<<<dim3(12, 1024), 256, 0, stream>>>(Abf, Wihb_i, b2i, gi_i, 65536, H3_, GP_, 0, 1, 1, 9);
    gemm_bf16_kernel<<<dim3(12, 64), 256, 0, stream>>>(Qbf, Wihb_q, b2q, gi_q, 4096, H3_, GP_, 0, 1, 1, 5);
    // --- both recurrences in one dispatch (blocks 0-7 input, 8-15 query) ---
    gru_rec_kernel<<<16, 512, 65536, stream>>>(Whh_i, bhh_i, gi_i, T_, EOS, S_, facts,
                                               Whh_q, bhh_q, gi_q, TQ_, qsl, 1, qvec);
    // --- episodes (3 dispatches each) ---
    uvec_kernel<<<128, 256, 0, stream>>>(zW, qvec, u_q, u_m, Mt);
    for (int ep = 0; ep < 3; ep++) {
        build_z_kernel<<<8192, 256, 0, stream>>>(facts, qvec, Mt, u_m, u_q, zbf);
        gemm_bf16_kernel<<<dim3(8, 128), 256, 0, stream>>>(zbf, gW1b, gb1, H1, 8192, GW_, ZP_, 1, 0, 0, 0);
        episode_tail_kernel<<<128, 256, 0, stream>>>(H1, gW2, gb2, facts,
                                                     WmxT, bih_m, WmhT, bhh_m, zW, Mt, u_m);
    }
    // --- fused answer head ---
    answer_kernel<<<128, 256, 0, stream>>>(Mt, Wa, qvec, WaxT, bih_a, WahT, bhh_a, (float*)d_out);
}

// Round 9
// 1731.750 us; speedup vs baseline: 1.1176x; 1.1176x over previous
//
#include <hip/hip_runtime.h>
#include <hip/hip_bf16.h>

// DMN model: GRU encoders + episodic attention + answer GRU.
// B=128 T=512 Tq=32 S=64 G=300 Hd=256 GW=512 V=159 Z=1794
#define B_   128
#define T_   512
#define TQ_  32
#define S_   64
#define G_   300
#define GP_  320      // G padded to mult of 32
#define HD_  256
#define GW_  512
#define V_   159
#define Z_   1794
#define ZP_  1824     // Z padded to mult of 32
#define H3_  768      // 3*Hd

using bf16x8 = __attribute__((ext_vector_type(8))) short;
using bf16x4 = __attribute__((ext_vector_type(4))) short;
using f32x4  = __attribute__((ext_vector_type(4))) float;

// ---- workspace layout (bytes) ----
#define OFF_WIHB_I 0u
#define OFF_WIHB_Q 491520u
#define OFF_GW1B   983040u        // 512x1824 bf16
#define OFF_FACTS  2850816u       // 128x64x256 f32
#define OFF_QVEC   11239424u      // 128x256 f32
#define OFF_UQ     11370496u
#define OFF_UM     11501568u
#define OFF_MT     11632640u
#define OFF_B2I    13139968u      // 768 f32 (bih + bhh for r,z)
#define OFF_B2Q    13143040u      // 768 f32
#define OFF_QBF    13500416u      // 4096x320 bf16 (own region; no Abf alias)
#define OFF_ABF    16777216u
#define OFF_GIQ    20971520u      // 8 chains x 32 t x 512 tid x 24 bf16
#define OFF_Z      29360128u      // 8192x1824 bf16 (ends 59.25 MB)
#define OFF_WMXT   59768832u      // Wih_m^T 256x768 f32
#define OFF_WMHT   60555264u      // Whh_m^T 256x768 f32
#define OFF_WAXT   61341696u      // Wih_a^T 415x768 f32
#define OFF_WAHT   62616576u      // Whh_a^T 256x768 f32 (ends 63.4 MB)
#define OFF_GII    67108864u      // 8 chains x 512 t x 512 tid x 24 bf16 (100.7 MB)
#define OFF_H1     67108864u      // reuses GII region after recurrence

// s_waitcnt immediate: lgkmcnt(0) only (vmcnt=63, expcnt=7 -> no wait)
#define WAIT_LGKM0() __builtin_amdgcn_s_waitcnt(0xC07F)

__device__ __forceinline__ unsigned short f2bf(float f) {
    unsigned int u = __float_as_uint(f);
    u += 0x7fffu + ((u >> 16) & 1u);          // round-to-nearest-even
    return (unsigned short)(u >> 16);
}
__device__ __forceinline__ float bf2f(unsigned short s) {
    return __uint_as_float(((unsigned int)s) << 16);
}
__device__ __forceinline__ float rcpf(float x) { return __builtin_amdgcn_rcpf(x); }
__device__ __forceinline__ float sigm(float x) { return rcpf(1.f + __expf(-x)); }
__device__ __forceinline__ float tanh_fast(float x) {
    float e = __expf(-2.f * fabsf(x));
    float t = (1.f - e) * rcpf(1.f + e);
    return copysignf(t, x);
}

// ---------------- f32 -> bf16 convert with K padding (input only) ----------------
__global__ void conv_pad_kernel(const float* __restrict__ src, unsigned short* __restrict__ dst,
                                int M, int K, int Kp) {
    int i = blockIdx.x * 256 + threadIdx.x;
    if (i >= M * Kp) return;
    int r = i / Kp, c = i - r * Kp;
    dst[i] = (c < K) ? f2bf(src[(size_t)r * K + c]) : (unsigned short)0;
}

// ---------------- merged prep: transposes, bias folds, bf16 weight/Q conversions ----------------
#define S1_ 196608    // 768x256 x3 transposes
#define S2_ 318720    // 768x415 transpose
#define S3_ 768       // bias folds
#define S4_ 245760    // Wihb_i + Wihb_q (768x320)
#define S5_ 933888    // gW1b (512x1824)
#define S6_ 1310720   // Qbf (4096x320)
#define PREP_TOT (S1_ + S2_ + S3_ + S4_ + S5_ + S6_)
__global__ void prep_kernel(
    const float* __restrict__ Wih_m, float* __restrict__ WmxT,
    const float* __restrict__ Whh_m, float* __restrict__ WmhT,
    const float* __restrict__ Wih_a, float* __restrict__ WaxT,
    const float* __restrict__ Whh_a, float* __restrict__ WahT,
    const float* __restrict__ bih_i, const float* __restrict__ bhh_i, float* __restrict__ b2i,
    const float* __restrict__ bih_q, const float* __restrict__ bhh_q, float* __restrict__ b2q,
    const float* __restrict__ Wih_i, unsigned short* __restrict__ Wihb_i,
    const float* __restrict__ Wih_q, unsigned short* __restrict__ Wihb_q,
    const float* __restrict__ gW1,   unsigned short* __restrict__ gW1b,
    const float* __restrict__ Qin,   unsigned short* __restrict__ Qbf)
{
    int i = blockIdx.x * 256 + threadIdx.x;
    if (i < S1_) {
        int r = i / 256, k = i - r * 256;
        WmxT[(size_t)k * 768 + r] = Wih_m[i];
        WmhT[(size_t)k * 768 + r] = Whh_m[i];
        WahT[(size_t)k * 768 + r] = Whh_a[i];
        return;
    }
    i -= S1_;
    if (i < S2_) {
        int r = i / 415, k = i - r * 415;
        WaxT[(size_t)k * 768 + r] = Wih_a[i];
        return;
    }
    i -= S2_;
    if (i < S3_) {
        b2i[i] = bih_i[i] + (i < 512 ? bhh_i[i] : 0.f);
        b2q[i] = bih_q[i] + (i < 512 ? bhh_q[i] : 0.f);
        return;
    }
    i -= S3_;
    if (i < S4_) {
        int r = i / GP_, c = i - r * GP_;
        Wihb_i[i] = (c < G_) ? f2bf(Wih_i[(size_t)r * G_ + c]) : (unsigned short)0;
        Wihb_q[i] = (c < G_) ? f2bf(Wih_q[(size_t)r * G_ + c]) : (unsigned short)0;
        return;
    }
    i -= S4_;
    if (i < S5_) {
        int r = i / ZP_, c = i - r * ZP_;
        gW1b[i] = (c < Z_) ? f2bf(gW1[(size_t)r * Z_ + c]) : (unsigned short)0;
        return;
    }
    i -= S5_;
    if (i < S6_) {
        int r = i / GP_, c = i - r * GP_;
        Qbf[i] = (c < G_) ? f2bf(Qin[(size_t)r * G_ + c]) : (unsigned short)0;
    }
}

// ---------------- bf16 MFMA GEMM: C[M,N] = act(A[M,Kp] @ W[N,Kp]^T + bias) ----------------
// mode 0: plain row-major out. mode 1: GRU gi permute to [c][t][tid][type][tt][i] bf16.
__global__ __launch_bounds__(256) void gemm_bf16_kernel(
    const unsigned short* __restrict__ A, const unsigned short* __restrict__ W,
    const float* __restrict__ bias, void* __restrict__ Cout,
    int M, int N, int Kp, int act, int out_bf16, int mode, int logT)
{
    __shared__ unsigned short As[64][40];
    __shared__ unsigned short Bs[64][40];
    int tid  = threadIdx.x;
    int wv   = tid >> 6, lane = tid & 63;
    int l15  = lane & 15, q = lane >> 4;
    int n0   = blockIdx.x * 64, m0 = blockIdx.y * 64;
    int r    = tid >> 2, p4 = tid & 3;

    const f32x4 zero4 = {0.f, 0.f, 0.f, 0.f};
    f32x4 acc[4] = {zero4, zero4, zero4, zero4};

    for (int k0 = 0; k0 < Kp; k0 += 32) {
        *(int4*)&As[r][p4 * 8] = *(const int4*)&A[(size_t)(m0 + r) * Kp + k0 + p4 * 8];
        *(int4*)&Bs[r][p4 * 8] = *(const int4*)&W[(size_t)(n0 + r) * Kp + k0 + p4 * 8];
        __syncthreads();
        bf16x8 af = *(const bf16x8*)&As[16 * wv + l15][q * 8];
#pragma unroll
        for (int nt = 0; nt < 4; nt++) {
            bf16x8 bf = *(const bf16x8*)&Bs[16 * nt + l15][q * 8];
            acc[nt] = __builtin_amdgcn_mfma_f32_16x16x32_bf16(af, bf, acc[nt], 0, 0, 0);
        }
        __syncthreads();
    }
    int rb = q * 4;
#pragma unroll
    for (int nt = 0; nt < 4; nt++) {
        int cgate = n0 + 16 * nt + l15;
        float bv = bias ? bias[cgate] : 0.f;
#pragma unroll
        for (int i = 0; i < 4; i++) {
            int row = m0 + 16 * wv + rb + i;
            float v = acc[nt][i] + bv;
            if (act == 1) v = tanh_fast(v);
            if (mode == 1) {
                int Tl = 1 << logT;
                int b = row >> logT, t = row & (Tl - 1);
                int cc = b >> 4, l = b & 15;
                int type = cgate >> 8, h = cgate & 255;
                int wvd = h >> 5, off = h & 31;
                int ttd = off >> 4, qd = (off >> 2) & 3, id = off & 3;
                int tidd = wvd * 64 + qd * 16 + l;
                size_t addr = ((size_t)(cc * Tl + t) * 512 + tidd) * 24 + type * 8 + ttd * 4 + id;
                ((unsigned short*)Cout)[addr] = f2bf(v);
            } else if (out_bf16) {
                ((unsigned short*)Cout)[(size_t)row * N + cgate] = f2bf(v);
            } else {
                ((float*)Cout)[(size_t)row * N + cgate] = v;
            }
        }
    }
}

// ---------------- persistent GRU recurrence (merged input+query) ----------------
// r6-exact version (measured 1013 us): 16 blocks x 512 threads. Transposed MFMA
// D[m=gate, n=batch]; 5 of 6 weight m-tiles in regs, n-tt1 tile in dynamic LDS.
// gi prefetched ONE step deep at end of step (2-deep variant regressed in r8).
__global__ __launch_bounds__(512, 2) void gru_rec_kernel(
    const float* __restrict__ Whh0, const float* __restrict__ bhh0,
    const unsigned short* __restrict__ gi0, int T0, const int* __restrict__ g0, int GL0,
    float* __restrict__ dst0,
    const float* __restrict__ Whh1, const float* __restrict__ bhh1,
    const unsigned short* __restrict__ gi1, int T1, const int* __restrict__ g1, int GL1,
    float* __restrict__ dst1)
{
    __shared__ unsigned short hfr[2][8][4][16][8];   // [buf][ks][q][batch][j] bf16 (16 KB)
    __shared__ int glist[16 * 64];
    __shared__ int gptr[16], gr0s[2][16], gr1s[2][16];
    extern __shared__ unsigned short wnL[];          // n-gate tt1 weights: [wv*8+ks][lane][8] (64 KB)

    int cb  = blockIdx.x;
    int tid = threadIdx.x;
    int wv  = tid >> 6, lane = tid & 63;
    int l15 = lane & 15, q = lane >> 4;

    const float* Whh; const float* bhh; const unsigned short* gi;
    const int* gidx; float* gdst; int T, GL, isq, c;
    if (cb < 8) { Whh = Whh0; bhh = bhh0; gi = gi0; T = T0; gidx = g0; GL = GL0; isq = 0; gdst = dst0; c = cb; }
    else        { Whh = Whh1; bhh = bhh1; gi = gi1; T = T1; gidx = g1; GL = GL1; isq = 1; gdst = dst1; c = cb - 8; }

    // ---- in-register A-fragments wf[mt][ks], mt: 0=r/tt0 1=r/tt1 2=z/tt0 3=z/tt1 4=n/tt0
    bf16x8 wf[5][8];
#pragma unroll
    for (int mt = 0; mt < 5; mt++) {
        int type = (mt < 4) ? (mt >> 1) : 2;
        int tt   = (mt < 4) ? (mt & 1) : 0;
        int g = type * 256 + 32 * wv + 16 * tt + l15;
#pragma unroll
        for (int ks = 0; ks < 8; ks++) {
            float4 w0 = *(const float4*)&Whh[(size_t)g * 256 + ks * 32 + q * 8];
            float4 w1 = *(const float4*)&Whh[(size_t)g * 256 + ks * 32 + q * 8 + 4];
            bf16x8 v;
            v[0] = (short)f2bf(w0.x); v[1] = (short)f2bf(w0.y);
            v[2] = (short)f2bf(w0.z); v[3] = (short)f2bf(w0.w);
            v[4] = (short)f2bf(w1.x); v[5] = (short)f2bf(w1.y);
            v[6] = (short)f2bf(w1.z); v[7] = (short)f2bf(w1.w);
            wf[mt][ks] = v;
        }
    }
    // ---- n-gate tt1 A-fragments into dynamic LDS (lane-contiguous, conflict-free) ----
    {
        int g = 512 + 32 * wv + 16 + l15;
#pragma unroll
        for (int ks = 0; ks < 8; ks++) {
            float4 w0 = *(const float4*)&Whh[(size_t)g * 256 + ks * 32 + q * 8];
            float4 w1 = *(const float4*)&Whh[(size_t)g * 256 + ks * 32 + q * 8 + 4];
            bf16x8 v;
            v[0] = (short)f2bf(w0.x); v[1] = (short)f2bf(w0.y);
            v[2] = (short)f2bf(w0.z); v[3] = (short)f2bf(w0.w);
            v[4] = (short)f2bf(w1.x); v[5] = (short)f2bf(w1.y);
            v[6] = (short)f2bf(w1.z); v[7] = (short)f2bf(w1.w);
            *(bf16x8*)&wnL[((wv * 8 + ks) * 64 + lane) * 8] = v;
        }
    }
    // bhh_n per-lane -> folded into MFMA C-operand init each step
    float bn[2][4];
#pragma unroll
    for (int tt = 0; tt < 2; tt++)
#pragma unroll
        for (int i = 0; i < 4; i++)
            bn[tt][i] = bhh[512 + 32 * wv + 16 * tt + 4 * q + i];

    // zero h-frag buffer 0 (first 8192 B)
    for (int i2 = tid; i2 < 2048; i2 += 512) ((int*)hfr)[i2] = 0;
    // gather list
    for (int i2 = tid; i2 < 16 * GL; i2 += 512) {
        int b = i2 / GL, s = i2 - b * GL;
        int raw = gidx[(c * 16 + b) * GL + s];
        if (isq) { raw -= 1; if (raw < 0) raw = 0; if (raw > T - 1) raw = T - 1; }
        glist[b * 64 + s] = raw;
    }
    __syncthreads();
    if (tid < 16) {                       // scan for t=0
        int p = 0;
        while (p < GL && glist[tid * 64 + p] == 0) p++;
        gr0s[0][tid] = 0; gr1s[0][tid] = p; gptr[tid] = p;
    }
    __syncthreads();

    float hprev[2][4] = {{0.f, 0.f, 0.f, 0.f}, {0.f, 0.f, 0.f, 0.f}};
    const unsigned short* gib = gi + (size_t)c * T * 12288;   // per-t: 512 tid * 24
    bf16x8 xa, xb, xc;     // gi for step t (r / z / n gates; bih [+bhh r,z] folded)
    {
        const unsigned short* pv = gib + (size_t)tid * 24;
        xa = *(const bf16x8*)pv;
        xb = *(const bf16x8*)(pv + 8);
        xc = *(const bf16x8*)(pv + 16);
    }

    const f32x4 zero4 = {0.f, 0.f, 0.f, 0.f};
    for (int t = 0; t < T; t++) {
        int cur = t & 1, nxt = cur ^ 1;
        // ---- scan gather list for t+1 (writes nxt slot; no race with cur) ----
        if (tid < 16) {
            int tt1 = t + 1;
            int p = gptr[tid], pp = p;
            while (p < GL && glist[tid * 64 + p] == tt1) p++;
            gr0s[nxt][tid] = pp; gr1s[nxt][tid] = p; gptr[tid] = p;
        }
        // ---- MFMA: acc[mt] = gh[gate][batch=l15]; n-gate C-init = bhh_n ----
        f32x4 acc[6];
        acc[0] = zero4; acc[1] = zero4; acc[2] = zero4; acc[3] = zero4;
        {
            f32x4 b4 = {bn[0][0], bn[0][1], bn[0][2], bn[0][3]}; acc[4] = b4;
            f32x4 b5 = {bn[1][0], bn[1][1], bn[1][2], bn[1][3]}; acc[5] = b5;
        }
#pragma unroll
        for (int ks = 0; ks < 8; ks++) {
            bf16x8 hb = *(const bf16x8*)&hfr[cur][ks][q][l15][0];
            acc[0] = __builtin_amdgcn_mfma_f32_16x16x32_bf16(wf[0][ks], hb, acc[0], 0, 0, 0);
            acc[1] = __builtin_amdgcn_mfma_f32_16x16x32_bf16(wf[1][ks], hb, acc[1], 0, 0, 0);
            acc[2] = __builtin_amdgcn_mfma_f32_16x16x32_bf16(wf[2][ks], hb, acc[2], 0, 0, 0);
            acc[3] = __builtin_amdgcn_mfma_f32_16x16x32_bf16(wf[3][ks], hb, acc[3], 0, 0, 0);
            acc[4] = __builtin_amdgcn_mfma_f32_16x16x32_bf16(wf[4][ks], hb, acc[4], 0, 0, 0);
            bf16x8 w5 = *(const bf16x8*)&wnL[((wv * 8 + ks) * 64 + lane) * 8];
            acc[5] = __builtin_amdgcn_mfma_f32_16x16x32_bf16(w5, hb, acc[5], 0, 0, 0);
        }
        // ---- elementwise GRU update (registers only) ----
        float h2a[2][4];
#pragma unroll
        for (int tt = 0; tt < 2; tt++) {
#pragma unroll
            for (int i = 0; i < 4; i++) {
                float r = sigm(bf2f((unsigned short)xa[tt * 4 + i]) + acc[tt][i]);
                float z = sigm(bf2f((unsigned short)xb[tt * 4 + i]) + acc[2 + tt][i]);
                float n = tanh_fast(bf2f((unsigned short)xc[tt * 4 + i]) + r * acc[4 + tt][i]);
                float h2 = (1.f - z) * n + z * hprev[tt][i];
                hprev[tt][i] = h2;
                h2a[tt][i] = h2;
            }
            bf16x4 hb;
#pragma unroll
            for (int i = 0; i < 4; i++) hb[i] = (short)f2bf(h2a[tt][i]);
            int qp = 2 * tt + (q >> 1), jb = 4 * (q & 1);
            *(bf16x4*)&hfr[nxt][wv][qp][l15][jb] = hb;   // hidden 32wv+16tt+4q+i, batch l15
        }
        // ---- gather writes (EOS / q_seq_len) ----
        {
            int p0 = gr0s[cur][l15], p1 = gr1s[cur][l15];
            for (int s = p0; s < p1; s++) {
                float* dp = &gdst[((size_t)(c * 16 + l15) * GL + s) * 256 + 32 * wv + 4 * q];
                float4 o0 = {h2a[0][0], h2a[0][1], h2a[0][2], h2a[0][3]};
                float4 o1 = {h2a[1][0], h2a[1][1], h2a[1][2], h2a[1][3]};
                *(float4*)dp        = o0;
                *(float4*)(dp + 16) = o1;
            }
        }
        // ---- prefetch gi for t+1 (operands consumed above; loads fly across barrier) ----
        {
            int tn = (t + 1 < T) ? (t + 1) : (T - 1);
            const unsigned short* pv = gib + ((size_t)tn * 512 + tid) * 24;
            xa = *(const bf16x8*)pv;
            xb = *(const bf16x8*)(pv + 8);
            xc = *(const bf16x8*)(pv + 16);
        }
        // ---- single barrier: LDS writes visible; vmcnt NOT drained ----
        __builtin_amdgcn_sched_barrier(0);
        WAIT_LGKM0();
        __builtin_amdgcn_s_barrier();
        __builtin_amdgcn_sched_barrier(0);
    }
}

// ---------------- u_q/u_m init + Mt=qvec ----------------
__global__ __launch_bounds__(256) void uvec_kernel(const float* __restrict__ zW,
                                                   const float* __restrict__ v,
                                                   float* __restrict__ u_q,
                                                   float* __restrict__ u_m,
                                                   float* __restrict__ Mt) {
    int b = blockIdx.x, h = threadIdx.x;
    float a = 0.f;
    for (int k = 0; k < 256; k++) a += zW[k * 256 + h] * v[b * 256 + k];
    u_q[b * 256 + h] = a;
    u_m[b * 256 + h] = a;          // Mt(ep0) == qvec
    Mt[b * 256 + h]  = v[b * 256 + h];
}

// ---------------- build z features (bf16, ZP cols) ----------------
__global__ __launch_bounds__(256) void build_z_kernel(
    const float* __restrict__ facts, const float* __restrict__ qv, const float* __restrict__ Mt,
    const float* __restrict__ u_m, const float* __restrict__ u_q, unsigned short* __restrict__ z)
{
    __shared__ float rm[4], rq[4], szm, szq;
    int bs = blockIdx.x;            // b*64+s
    int b  = bs >> 6;
    int j  = threadIdx.x;
    float C  = facts[(size_t)bs * 256 + j];
    float m  = Mt[b * 256 + j];
    float qq = qv[b * 256 + j];
    float dm = C * u_m[b * 256 + j];
    float dq = C * u_q[b * 256 + j];
    for (int o = 32; o; o >>= 1) { dm += __shfl_down(dm, o); dq += __shfl_down(dq, o); }
    int wvi = j >> 6;
    if ((j & 63) == 0) { rm[wvi] = dm; rq[wvi] = dq; }
    __syncthreads();
    if (j == 0) { szm = rm[0] + rm[1] + rm[2] + rm[3]; szq = rq[0] + rq[1] + rq[2] + rq[3]; }
    __syncthreads();
    size_t zr = (size_t)bs * ZP_;
    z[zr + j]        = f2bf(C);
    z[zr + 256 + j]  = f2bf(qq);
    z[zr + 512 + j]  = f2bf(m);
    z[zr + 768 + j]  = f2bf(C * m);
    z[zr + 1024 + j] = f2bf(C * qq);
    z[zr + 1280 + j] = f2bf(fabsf(C - m));
    z[zr + 1536 + j] = f2bf(fabsf(C - qq));
    if (j == 0) { z[zr + 1792] = f2bf(szm); z[zr + 1793] = f2bf(szq); }
    if (j < ZP_ - Z_) z[zr + Z_ + j] = 0;
}

// ---------------- fused episode tail: g-reduce + softmax + Htc + GRU cell + u_m ----------------
// one block per batch row b, 256 threads.
__global__ __launch_bounds__(256) void episode_tail_kernel(
    const float* __restrict__ H1, const float* __restrict__ gW2, const float* __restrict__ gb2,
    const float* __restrict__ facts,
    const float* __restrict__ WmxT, const float* __restrict__ bxm,
    const float* __restrict__ WmhT, const float* __restrict__ bhm,
    const float* __restrict__ zW,
    float* __restrict__ Mt, float* __restrict__ u_m)
{
    __shared__ float red[64][4];
    __shared__ float p64[64];
    __shared__ float xs[256];   // Htc
    __shared__ float hs[256];   // Mt old
    __shared__ float hs2[256];  // Mt new
    int b = blockIdx.x, tid = threadIdx.x;
    // stage 1: att pre-activation partials
    {
        int s = tid >> 2, part = tid & 3;
        const float* h1r = H1 + ((size_t)(b * 64 + s)) * 512 + part * 128;
        const float* w2  = gW2 + part * 128;
        float a = 0.f;
        for (int k = 0; k < 128; k++) a += h1r[k] * w2[k];
        red[s][part] = a;
    }
    hs[tid] = Mt[b * 256 + tid];
    __syncthreads();
    // stage 2: att + softmax over 64 (wave 0)
    if (tid < 64) {
        float att = sigm(red[tid][0] + red[tid][1] + red[tid][2] + red[tid][3] + gb2[0]);
        float mx = att;
        for (int o = 32; o; o >>= 1) mx = fmaxf(mx, __shfl_xor(mx, o));
        float e = __expf(att - mx);
        float sm = e;
        for (int o = 32; o; o >>= 1) sm += __shfl_xor(sm, o);
        p64[tid] = e * rcpf(sm);
    }
    __syncthreads();
    // stage 3: Htc
    {
        float a = 0.f;
        for (int s = 0; s < 64; s++) a += facts[((size_t)b * 64 + s) * 256 + tid] * p64[s];
        xs[tid] = a;
    }
    __syncthreads();
    // stage 4: GRU cell (x=Htc, h=Mt)
    {
        int j = tid;
        float ar = bxm[j], az = bxm[256 + j], an = bxm[512 + j];
        for (int k = 0; k < 256; k++) {
            float xv = xs[k];
            const float* wr = &WmxT[(size_t)k * 768];
            ar += xv * wr[j]; az += xv * wr[256 + j]; an += xv * wr[512 + j];
        }
        float hr = bhm[j], hz = bhm[256 + j], hn = bhm[512 + j];
        for (int k = 0; k < 256; k++) {
            float hv = hs[k];
            const float* wr = &WmhT[(size_t)k * 768];
            hr += hv * wr[j]; hz += hv * wr[256 + j]; hn += hv * wr[512 + j];
        }
        float r = sigm(ar + hr);
        float z = sigm(az + hz);
        float n = tanh_fast(an + r * hn);
        float h2 = (1.f - z) * n + z * hs[j];
        Mt[b * 256 + j] = h2;
        hs2[j] = h2;
    }
    __syncthreads();
    // stage 5: u_m for next episode
    {
        float a = 0.f;
        for (int k = 0; k < 256; k++) a += zW[k * 256 + tid] * hs2[k];
        u_m[b * 256 + tid] = a;
    }
}

// ---------------- fused answer head: softmax(Mt@Wa^T) -> concat(yt, qvec) -> GRU cell -> softmax ----------------
__global__ __launch_bounds__(256) void answer_kernel(
    const float* __restrict__ Mt, const float* __restrict__ Wa, const float* __restrict__ qv,
    const float* __restrict__ WaxT, const float* __restrict__ bxa,
    const float* __restrict__ WahT, const float* __restrict__ bha,
    float* __restrict__ out)
{
    __shared__ float sc[V_];
    __shared__ float xs[416];
    __shared__ float hs[256], hs2[256];
    int b = blockIdx.x, tid = threadIdx.x;
    hs[tid] = Mt[b * 256 + tid];
    xs[V_ + tid] = qv[b * 256 + tid];    // xt[159:415] = q  (reference: concat([yt, q]))
    __syncthreads();
    if (tid < V_) {
        float a = 0.f;
        for (int k = 0; k < 256; k++) a += hs[k] * Wa[(size_t)tid * 256 + k];
        sc[tid] = a;
    }
    __syncthreads();
    if (tid == 0) {
        float mx = -1e30f;
        for (int v = 0; v < V_; v++) mx = fmaxf(mx, sc[v]);
        float sm = 0.f;
        for (int v = 0; v < V_; v++) { float e = __expf(sc[v] - mx); sc[v] = e; sm += e; }
        float inv = rcpf(sm);
        for (int v = 0; v < V_; v++) sc[v] *= inv;
    }
    __syncthreads();
    if (tid < V_) xs[tid] = sc[tid];     // xt[0:159] = yt
    __syncthreads();
    // GRU cell (x=xt[415], h=at=Mt)
    {
        int j = tid;
        float ar = bxa[j], az = bxa[256 + j], an = bxa[512 + j];
        for (int k = 0; k < 415; k++) {
            float xv = xs[k];
            const float* wr = &WaxT[(size_t)k * 768];
            ar += xv * wr[j]; az += xv * wr[256 + j]; an += xv * wr[512 + j];
        }
        float hr = bha[j], hz = bha[256 + j], hn = bha[512 + j];
        for (int k = 0; k < 256; k++) {
            float hv = hs[k];
            const float* wr = &WahT[(size_t)k * 768];
            hr += hv * wr[j]; hz += hv * wr[256 + j]; hn += hv * wr[512 + j];
        }
        float r = sigm(ar + hr);
        float z = sigm(az + hz);
        float n = tanh_fast(an + r * hn);
        hs2[j] = (1.f - z) * n + z * hs[j];
    }
    __syncthreads();
    if (tid < V_) {
        float a = 0.f;
        for (int k = 0; k < 256; k++) a += hs2[k] * Wa[(size_t)tid * 256 + k];
        sc[tid] = a;
    }
    __syncthreads();
    if (tid == 0) {
        float mx = -1e30f;
        for (int v = 0; v < V_; v++) mx = fmaxf(mx, sc[v]);
        float sm = 0.f;
        for (int v = 0; v < V_; v++) { float e = __expf(sc[v] - mx); sc[v] = e; sm += e; }
        float inv = rcpf(sm);
        for (int v = 0; v < V_; v++) sc[v] *= inv;
    }
    __syncthreads();
    if (tid < V_) out[b * V_ + tid] = sc[tid];
}

extern "C" void kernel_launch(void* const* d_in, const int* in_sizes, int n_in,
                              void* d_out, int out_size, void* d_ws, size_t ws_size,
                              hipStream_t stream) {
    (void)in_sizes; (void)n_in; (void)out_size; (void)ws_size;
    const float* input = (const float*)d_in[0];
    const float* Qin   = (const float*)d_in[1];
    const int*   EOS   = (const int*)d_in[2];
    const int*   qsl   = (const int*)d_in[3];
    const float* Wih_i = (const float*)d_in[6];
    const float* Whh_i = (const float*)d_in[7];
    const float* bih_i = (const float*)d_in[8];
    const float* bhh_i = (const float*)d_in[9];
    const float* Wih_q = (const float*)d_in[10];
    const float* Whh_q = (const float*)d_in[11];
    const float* bih_q = (const float*)d_in[12];
    const float* bhh_q = (const float*)d_in[13];
    const float* zW    = (const float*)d_in[14];
    const float* gW1   = (const float*)d_in[15];
    const float* gb1   = (const float*)d_in[16];
    const float* gW2   = (const float*)d_in[17];
    const float* gb2   = (const float*)d_in[18];
    const float* Wih_m = (const float*)d_in[19];
    const float* Whh_m = (const float*)d_in[20];
    const float* bih_m = (const float*)d_in[21];
    const float* bhh_m = (const float*)d_in[22];
    const float* Wa    = (const float*)d_in[23];
    const float* Wih_a = (const float*)d_in[24];
    const float* Whh_a = (const float*)d_in[25];
    const float* bih_a = (const float*)d_in[26];
    const float* bhh_a = (const float*)d_in[27];

    char* ws = (char*)d_ws;
    unsigned short* Wihb_i = (unsigned short*)(ws + OFF_WIHB_I);
    unsigned short* Wihb_q = (unsigned short*)(ws + OFF_WIHB_Q);
    unsigned short* gW1b   = (unsigned short*)(ws + OFF_GW1B);
    float* facts = (float*)(ws + OFF_FACTS);
    float* qvec  = (float*)(ws + OFF_QVEC);
    float* u_q   = (float*)(ws + OFF_UQ);
    float* u_m   = (float*)(ws + OFF_UM);
    float* Mt    = (float*)(ws + OFF_MT);
    float* b2i   = (float*)(ws + OFF_B2I);
    float* b2q   = (float*)(ws + OFF_B2Q);
    float* WmxT  = (float*)(ws + OFF_WMXT);
    float* WmhT  = (float*)(ws + OFF_WMHT);
    float* WaxT  = (float*)(ws + OFF_WAXT);
    float* WahT  = (float*)(ws + OFF_WAHT);
    unsigned short* Abf  = (unsigned short*)(ws + OFF_ABF);
    unsigned short* Qbf  = (unsigned short*)(ws + OFF_QBF);
    unsigned short* gi_q = (unsigned short*)(ws + OFF_GIQ);
    unsigned short* zbf  = (unsigned short*)(ws + OFF_Z);
    unsigned short* gi_i = (unsigned short*)(ws + OFF_GII);
    float* H1 = (float*)(ws + OFF_H1);

    hipFuncSetAttribute((const void*)gru_rec_kernel,
                        hipFuncAttributeMaxDynamicSharedMemorySize, 65536);

    // --- conversions + merged prep ---
    conv_pad_kernel<<<(65536 * GP_ + 255) / 256, 256, 0, stream>>>(input, Abf, 65536, G_, GP_);
    prep_kernel<<<(PREP_TOT + 255) / 256, 256, 0, stream>>>(
        Wih_m, WmxT, Whh_m, WmhT, Wih_a, WaxT, Whh_a, WahT,
        bih_i, bhh_i, b2i, bih_q, bhh_q, b2q,
        Wih_i, Wihb_i, Wih_q, Wihb_q, gW1, gW1b, Qin, Qbf);
    // --- gi GEMMs (output permuted to [c][t][tid][24], bih+bhh(r,z) folded) ---
    gemm_bf16_kernel<<<dim3(12, 1024), 256, 0, stream>>>(Abf, Wihb_i, b2i, gi_i, 65536, H3_, GP_, 0, 1, 1, 9);
    gemm_bf16_kernel<<<dim3(12, 64), 256, 0, stream>>>(Qbf, Wihb_q, b2q, gi_q, 4096, H3_, GP_, 0, 1, 1, 5);
    // --- both recurrences in one dispatch (blocks 0-7 input, 8-15 query) ---
    gru_rec_kernel<<<16, 512, 65536, stream>>>(Whh_i, bhh_i, gi_i, T_, EOS, S_, facts,
                                               Whh_q, bhh_q, gi_q, TQ_, qsl, 1, qvec);
    // --- episodes (3 dispatches each) ---
    uvec_kernel<<<128, 256, 0, stream>>>(zW, qvec, u_q, u_m, Mt);
    for (int ep = 0; ep < 3; ep++) {
        build_z_kernel<<<8192, 256, 0, stream>>>(facts, qvec, Mt, u_m, u_q, zbf);
        gemm_bf16_kernel<<<dim3(8, 128), 256, 0, stream>>>(zbf, gW1b, gb1, H1, 8192, GW_, ZP_, 1, 0, 0, 0);
        episode_tail_kernel<<<128, 256, 0, stream>>>(H1, gW2, gb2, facts,
                                                     WmxT, bih_m, WmhT, bhh_m, zW, Mt, u_m);
    }
    // --- fused answer head ---
    answer_kernel<<<128, 256, 0, stream>>>(Mt, Wa, qvec, WaxT, bih_a, WahT, bhh_a, (float*)d_out);
}